// Round 1
// baseline (103.560 us; speedup 1.0000x reference)
//
#include <hip/hip_runtime.h>
#include <hip/hip_bf16.h>

#define NPTS 384
#define DIMS 256
#define TI 4      // i-rows per block in main kernel
#define JC 48     // j-columns per block in main kernel

// ---------------------------------------------------------------------------
// Kernel 1: Gram matrices G = E * E^T for both student and teacher (grid.z).
// 32x32 output tile per block, 256 threads, 2x2 micro-tile per thread.
// ---------------------------------------------------------------------------
__global__ void gram_kernel(const float* __restrict__ Es, const float* __restrict__ Et,
                            float* __restrict__ Gs, float* __restrict__ Gt) {
    const float* __restrict__ E = (blockIdx.z == 0) ? Es : Et;
    float* __restrict__ G       = (blockIdx.z == 0) ? Gs : Gt;

    __shared__ float As[32][33];
    __shared__ float Bs[32][33];

    const int tx = threadIdx.x;          // 0..15
    const int ty = threadIdx.y;          // 0..15
    const int t  = ty * 16 + tx;         // 0..255
    const int lr = t >> 5;               // 0..7
    const int lc = t & 31;               // 0..31
    const int i0 = blockIdx.x * 32;
    const int j0 = blockIdx.y * 32;

    float acc00 = 0.f, acc01 = 0.f, acc10 = 0.f, acc11 = 0.f;

    for (int k0 = 0; k0 < DIMS; k0 += 32) {
#pragma unroll
        for (int rr = 0; rr < 4; rr++) {
            As[lr + 8 * rr][lc] = E[(i0 + lr + 8 * rr) * DIMS + k0 + lc];
            Bs[lr + 8 * rr][lc] = E[(j0 + lr + 8 * rr) * DIMS + k0 + lc];
        }
        __syncthreads();
#pragma unroll
        for (int k = 0; k < 32; k++) {
            float a0 = As[2 * ty][k], a1 = As[2 * ty + 1][k];
            float b0 = Bs[2 * tx][k], b1 = Bs[2 * tx + 1][k];
            acc00 = fmaf(a0, b0, acc00);
            acc01 = fmaf(a0, b1, acc01);
            acc10 = fmaf(a1, b0, acc10);
            acc11 = fmaf(a1, b1, acc11);
        }
        __syncthreads();
    }

    const int i = i0 + 2 * ty;
    const int j = j0 + 2 * tx;
    G[i * NPTS + j]           = acc00;
    G[i * NPTS + j + 1]       = acc01;
    G[(i + 1) * NPTS + j]     = acc10;
    G[(i + 1) * NPTS + j + 1] = acc11;
}

// ---------------------------------------------------------------------------
// Kernel 2: inverse-norm matrices R[i][j] = 1/||e_i - e_j||, 0 on diagonal.
// ||e_i - e_j||^2 = G_ii - 2 G_ij + G_jj.  grid.y selects matrix.
// ---------------------------------------------------------------------------
__global__ void invnorm_kernel(const float* __restrict__ Gs, const float* __restrict__ Gt,
                               float* __restrict__ Rs, float* __restrict__ Rt) {
    const float* __restrict__ G = (blockIdx.y == 0) ? Gs : Gt;
    float* __restrict__ R       = (blockIdx.y == 0) ? Rs : Rt;

    int idx = blockIdx.x * 256 + threadIdx.x;
    if (idx >= NPTS * NPTS) return;
    int i = idx / NPTS;
    int j = idx - i * NPTS;

    float gii = G[i * NPTS + i];
    float gjj = G[j * NPTS + j];
    float v   = gii - 2.0f * G[idx] + gjj;
    float n   = sqrtf(fmaxf(v, 0.0f));
    float r   = 1.0f / fmaxf(n, 1e-12f);
    R[idx] = (i == j) ? 0.0f : r;
}

// ---------------------------------------------------------------------------
// Kernel 3: main triple-loop reduction.
// Block: i-tile of TI rows, j-chunk of JC columns, 384 threads (thread == k).
// angle_ijk = r_ij * fma(r_ik, G_jk + (G_ii - G_ij), -r_ik*G_ik)
// (r on diagonal == 0 masks j==i and k==i exactly, matching the reference)
// ---------------------------------------------------------------------------
__global__ __launch_bounds__(NPTS) void rkd_angle_kernel(
        const float* __restrict__ Gs, const float* __restrict__ Gt,
        const float* __restrict__ Rs, const float* __restrict__ Rt,
        float* __restrict__ out) {
    __shared__ float sGs[TI][NPTS];
    __shared__ float sGt[TI][NPTS];
    __shared__ float sRs[TI][NPTS];
    __shared__ float sRt[TI][NPTS];

    const int tid = threadIdx.x;           // 0..383, also k
    const int i0  = blockIdx.x * TI;
    const int j0  = blockIdx.y * JC;

#pragma unroll
    for (int r = 0; r < TI; r++) {
        int row = (i0 + r) * NPTS;
        sGs[r][tid] = Gs[row + tid];
        sGt[r][tid] = Gt[row + tid];
        sRs[r][tid] = Rs[row + tid];
        sRt[r][tid] = Rt[row + tid];
    }
    __syncthreads();

    const int k = tid;
    float gii_s[TI], gii_t[TI], rik_s[TI], rik_t[TI], qik_s[TI], qik_t[TI];
#pragma unroll
    for (int r = 0; r < TI; r++) {
        gii_s[r] = sGs[r][i0 + r];
        gii_t[r] = sGt[r][i0 + r];
        rik_s[r] = sRs[r][k];
        rik_t[r] = sRt[r][k];
        qik_s[r] = rik_s[r] * sGs[r][k];
        qik_t[r] = rik_t[r] * sGt[r][k];
    }

    float acc = 0.0f;
    for (int j = j0; j < j0 + JC; j++) {
        float gs_jk = Gs[j * NPTS + k];
        float gt_jk = Gt[j * NPTS + k];
#pragma unroll
        for (int r = 0; r < TI; r++) {
            float cs = gii_s[r] - sGs[r][j];
            float as = sRs[r][j] * fmaf(rik_s[r], gs_jk + cs, -qik_s[r]);
            float ct = gii_t[r] - sGt[r][j];
            float at = sRt[r][j] * fmaf(rik_t[r], gt_jk + ct, -qik_t[r]);
            float x  = fabsf(as - at);
            acc += (x < 1.0f) ? 0.5f * x * x : x - 0.5f;
        }
    }

    // wave reduce (64-wide)
#pragma unroll
    for (int off = 32; off > 0; off >>= 1)
        acc += __shfl_down(acc, off, 64);

    __shared__ float wsum[NPTS / 64];
    const int wid  = tid >> 6;
    const int lane = tid & 63;
    if (lane == 0) wsum[wid] = acc;
    __syncthreads();
    if (tid == 0) {
        float s = 0.0f;
#pragma unroll
        for (int w = 0; w < NPTS / 64; w++) s += wsum[w];
        atomicAdd(out, s * (1.0f / (384.0f * 384.0f * 384.0f)));
    }
}

extern "C" void kernel_launch(void* const* d_in, const int* in_sizes, int n_in,
                              void* d_out, int out_size, void* d_ws, size_t ws_size,
                              hipStream_t stream) {
    const float* student = (const float*)d_in[0];
    const float* teacher = (const float*)d_in[1];
    float* out = (float*)d_out;

    // workspace layout: Gs, Gt, Rs, Rt — each NPTS*NPTS floats
    float* Gs = (float*)d_ws;
    float* Gt = Gs + NPTS * NPTS;
    float* Rs = Gt + NPTS * NPTS;
    float* Rt = Rs + NPTS * NPTS;

    hipMemsetAsync(d_out, 0, sizeof(float), stream);

    dim3 ggrid(NPTS / 32, NPTS / 32, 2);
    dim3 gblock(16, 16, 1);
    gram_kernel<<<ggrid, gblock, 0, stream>>>(student, teacher, Gs, Gt);

    dim3 ngrid((NPTS * NPTS + 255) / 256, 2, 1);
    invnorm_kernel<<<ngrid, 256, 0, stream>>>(Gs, Gt, Rs, Rt);

    dim3 mgrid(NPTS / TI, NPTS / JC, 1);
    rkd_angle_kernel<<<mgrid, NPTS, 0, stream>>>(Gs, Gt, Rs, Rt, out);
}